// Round 2
// baseline (274.012 us; speedup 1.0000x reference)
//
#include <hip/hip_runtime.h>
#include <math.h>

// HOG (skimage-faithful): orientations=8, cell=16x16, 1x1 blocks, L2-Hys.
// Input: fake [B,3,512,512] f32 (NCHW). Output: [B, 32*32*8] f32.
//
// Round 5 (resubmit after infra failure): cut redundant global fetch +
// register pressure. R4 preloaded R[6][3] float4 (72 VGPRs, rows r0-1..r0+4)
// per wave, so each block issued 24 row-loads for 18 distinct rows (1.33x)
// and sat at ~120 VGPR against the 128 cap from __launch_bounds__(256,4).
// Now each wave loads only its OWN 4 rows (R[4][3], 48 VGPRs); inter-wave
// boundary rows are exchanged via a 24KB LDS buffer (wave w publishes
// row0/row3; waves 0/3 fetch the block's top/bottom halo row once). Up/down
// rows are read from LDS only at hh==0 / hh==3, so they are transient.
// Issued global bytes/block: 72KB -> 55KB.
//
// Block = 256 = 4 waves stacked vertically; wave = 4 rows x 256 cols
// (4 px/lane). Block covers one cell-row x half the image width.
// Grid = B * 32 cellrows * 2 colhalves.

namespace {

constexpr int Hh = 512;
constexpr int Ww = 512;
constexpr int CHN = 3;
constexpr int HW = Hh * Ww;
constexpr float TAN22 = 0.41421356237309503f;  // tan(22.5 deg)

__global__ __launch_bounds__(256, 4) void hog_kernel(const float* __restrict__ x,
                                                     float* __restrict__ out) {
    const int b       = blockIdx.x >> 6;
    const int cellrow = (blockIdx.x >> 1) & 31;
    const int colhalf = blockIdx.x & 1;
    const int tx      = threadIdx.x;
    const int lane    = tx & 63;
    const int wid     = tx >> 6;               // 0..3: 4-row strip in the cell-row
    const int r0      = cellrow * 16 + wid * 4;
    const int c0      = colhalf << 8;          // 0 or 256

    const float* xb = x + (size_t)b * (CHN * HW);

    // ---- each wave loads ONLY its own 4 rows x 3 ch (12 float4 loads) ----
    float4 R[4][CHN];
#pragma unroll
    for (int r = 0; r < 4; ++r)
#pragma unroll
        for (int ch = 0; ch < CHN; ++ch)
            R[r][ch] = *(const float4*)(xb + (size_t)ch * HW +
                                        (size_t)(r0 + r) * Ww + c0 + (lane << 2));

    // ---- inter-wave row exchange via LDS ----
    // slots: 0=top halo, 1=w0r3, 2=w1r0, 3=w1r3, 4=w2r0, 5=w2r3, 6=w3r0, 7=bot
    __shared__ float4 xrows[8][CHN][64];       // 24.6 KB
    if (wid > 0)
#pragma unroll
        for (int ch = 0; ch < CHN; ++ch) xrows[2 * wid][ch][lane] = R[0][ch];
    if (wid < 3)
#pragma unroll
        for (int ch = 0; ch < CHN; ++ch) xrows[2 * wid + 1][ch][lane] = R[3][ch];
    if (wid == 0) {                            // block-top halo row (clamped;
        int h = r0 - 1;                        //  clamped case feeds a forced-
        h = h < 0 ? 0 : h;                     //  zero row-edge gradient anyway)
#pragma unroll
        for (int ch = 0; ch < CHN; ++ch)
            xrows[0][ch][lane] = *(const float4*)(xb + (size_t)ch * HW +
                                                  (size_t)h * Ww + c0 + (lane << 2));
    }
    if (wid == 3) {                            // block-bottom halo row
        int h = r0 + 4;
        h = h > Hh - 1 ? Hh - 1 : h;
#pragma unroll
        for (int ch = 0; ch < CHN; ++ch)
            xrows[7][ch][lane] = *(const float4*)(xb + (size_t)ch * HW +
                                                  (size_t)h * Ww + c0 + (lane << 2));
    }

    // ---- all 24 col-seam halo scalars in one exec-masked load (lanes 0..23) ----
    // lane = ch<<3 | row<<1 | side;  side 0 = col c0-1, side 1 = col c0+256
    float halov = 0.f;
    if (lane < 24) {
        const int ch = lane >> 3, r = (lane >> 1) & 3, side = lane & 1;
        int wcol = side ? c0 + 256 : c0 - 1;
        wcol = wcol < 0 ? 0 : (wcol > Ww - 1 ? Ww - 1 : wcol);  // clamped cases
        halov = xb[(size_t)ch * HW + (size_t)(r0 + r) * Ww + wcol];  // are the
    }                                                 // forced-zero col borders

    __syncthreads();

    const int upSlot = (wid == 0) ? 0 : 2 * wid - 1;
    const int dnSlot = (wid == 3) ? 7 : 2 * wid + 2;

    const bool bL = (colhalf == 0) & (lane == 0);     // w == 0
    const bool bR = (colhalf == 1) & (lane == 63);    // w == 511

    float c[8];                              // cumulative thermometer histogram
#pragma unroll
    for (int o = 0; o < 8; ++o) c[o] = 0.f;

#pragma unroll
    for (int hh = 0; hh < 4; ++hh) {
        const int h = r0 + hh;
        const bool rowEdge = (h == 0) | (h == Hh - 1);

        // prev/next rows: registers in the interior, LDS at the strip edges
        float4 P[CHN], N[CHN];
#pragma unroll
        for (int ch = 0; ch < CHN; ++ch) {
            P[ch] = (hh == 0) ? xrows[upSlot][ch][lane] : R[(hh > 0) ? hh - 1 : 0][ch];
            N[ch] = (hh == 3) ? xrows[dnSlot][ch][lane] : R[(hh < 3) ? hh + 1 : 3][ch];
        }

        // left/right neighbors across lanes (+ block-seam halo broadcast)
        float gL[CHN], gR[CHN];
#pragma unroll
        for (int ch = 0; ch < CHN; ++ch) {
            const float su = __shfl_up(R[hh][ch].w, 1, 64);
            const float sd = __shfl_down(R[hh][ch].x, 1, 64);
            const float hl = __shfl(halov, (ch << 3) | (hh << 1), 64);
            const float hr = __shfl(halov, (ch << 3) | (hh << 1) | 1, 64);
            gL[ch] = (lane == 0)  ? hl : su;
            gR[ch] = (lane == 63) ? hr : sd;
        }

#pragma unroll
        for (int i = 0; i < 4; ++i) {
            float bm2 = -1.f, bgr = 0.f, bgc = 0.f;
#pragma unroll
            for (int ch = 0; ch < CHN; ++ch) {
                const float4 pv = P[ch];
                const float4 cv = R[hh][ch];
                const float4 nv = N[ch];
                const float pr_[4] = {pv.x, pv.y, pv.z, pv.w};
                const float cu_[4] = {cv.x, cv.y, cv.z, cv.w};
                const float nx_[4] = {nv.x, nv.y, nv.z, nv.w};
                const float gl  = (i == 0) ? gL[ch] : cu_[i - 1];
                const float gr_ = (i == 3) ? gR[ch] : cu_[i + 1];
                float gcol = gr_ - gl;
                if (i == 0) gcol = bL ? 0.f : gcol;    // image col borders
                if (i == 3) gcol = bR ? 0.f : gcol;
                float gv = nx_[i] - pr_[i];
                gv = rowEdge ? 0.f : gv;               // image row borders
                const float m2 = fmaf(gv, gv, gcol * gcol);
                if (m2 > bm2) { bm2 = m2; bgr = gv; bgc = gcol; }  // first-max
            }
            const float m = sqrtf(bm2);

            // flip into upper half-plane; (gr==0, gc<0) -> 180 deg -> bin 0
            const bool flip = (bgr < 0.f) | ((bgr == 0.f) & (bgc < 0.f));
            const float bb = flip ? -bgr : bgr;        // >= 0
            const float A  = flip ? -bgc : bgc;
            const float Aa = fabsf(A);
            const float p1 = Aa * TAN22;
            const float p2 = bb * TAN22;
            const bool q2  = (A <= 0.f);               // ori >= 90
            const bool ge1 = (bb >= p1), ge2 = (bb >= Aa), ge3 = (p2 >= Aa);
            const bool gt1 = (bb > p1),  gt2 = (bb > Aa),  gt3 = (p2 > Aa);
            // c[k] == sum of m where ori >= 22.5k; hist by differencing later
            c[0] += m;
            c[1] += (q2 | ge1) ? m : 0.f;
            c[2] += (q2 | ge2) ? m : 0.f;
            c[3] += (q2 | ge3) ? m : 0.f;
            c[4] += q2 ? m : 0.f;
            c[5] += (q2 & !gt3) ? m : 0.f;
            c[6] += (q2 & !gt2) ? m : 0.f;
            c[7] += (q2 & !gt1) ? m : 0.f;
        }
    }

    // 4 consecutive lanes = one 16-col cell: pairwise shuffle reduce
#pragma unroll
    for (int o = 0; o < 8; ++o) {
        c[o] += __shfl_xor(c[o], 1, 64);
        c[o] += __shfl_xor(c[o], 2, 64);
    }

    __shared__ float lh[4][16][9];           // [strip][cell][bin], col 8 = 0
    if (tx < 64) lh[tx >> 4][tx & 15][8] = 0.f;
    if ((lane & 3) == 0) {
        const int cell = lane >> 2;
#pragma unroll
        for (int o = 0; o < 8; ++o) lh[wid][cell][o] = c[o];
    }
    __syncthreads();

    // 128 threads -> (cell 0..15, bin 0..7): finish hist + L2-Hys
    if (tx < 128) {
        const int cell = tx >> 3;
        const int o    = tx & 7;
        const float c_o  = lh[0][cell][o]     + lh[1][cell][o] +
                           lh[2][cell][o]     + lh[3][cell][o];
        const float c_o1 = lh[0][cell][o + 1] + lh[1][cell][o + 1] +
                           lh[2][cell][o + 1] + lh[3][cell][o + 1];
        const float hv = (c_o - c_o1) * (1.0f / 256.0f);   // cell mean

        float ss = hv * hv;                  // L2-Hys over the 8-bin group
        ss += __shfl_xor(ss, 1, 64);
        ss += __shfl_xor(ss, 2, 64);
        ss += __shfl_xor(ss, 4, 64);
        float n1 = hv / sqrtf(ss + 1e-10f);  // eps^2 = (1e-5)^2
        n1 = fminf(n1, 0.2f);
        float s2 = n1 * n1;
        s2 += __shfl_xor(s2, 1, 64);
        s2 += __shfl_xor(s2, 2, 64);
        s2 += __shfl_xor(s2, 4, 64);
        const float nv = n1 / sqrtf(s2 + 1e-10f);

        out[(((size_t)b * 32 + cellrow) * 32 + (colhalf * 16 + cell)) * 8 + o] = nv;
    }
}

} // namespace

extern "C" void kernel_launch(void* const* d_in, const int* in_sizes, int n_in,
                              void* d_out, int out_size, void* d_ws, size_t ws_size,
                              hipStream_t stream) {
    (void)n_in; (void)out_size; (void)d_ws; (void)ws_size;
    const float* x = (const float*)d_in[0];
    float* out = (float*)d_out;
    const int B = in_sizes[0] / (CHN * HW);   // 64 for the bench shape
    const int grid = B * 32 * 2;              // batch * cellrows * colhalves
    hog_kernel<<<grid, 256, 0, stream>>>(x, out);
}